// Round 2
// baseline (306.538 us; speedup 1.0000x reference)
//
#include <hip/hip_runtime.h>
#include <hip/hip_bf16.h>
#include <cstdint>

#define NB 16
#define NC 512
#define NPIX 1024
#define NHEADS 4
#define NEMB 128

typedef short bf16x8 __attribute__((ext_vector_type(8)));
typedef float f32x4 __attribute__((ext_vector_type(4)));
typedef unsigned short u16x4 __attribute__((ext_vector_type(4)));
typedef unsigned short u16x8 __attribute__((ext_vector_type(8)));

__device__ __forceinline__ unsigned short f2bf(float f) {
  union { float f; unsigned u; } c; c.f = f;
  return (unsigned short)((c.u + 0x7FFFu + ((c.u >> 16) & 1u)) >> 16);
}

__device__ __forceinline__ void gload_lds16(const void* g, void* l) {
  __builtin_amdgcn_global_load_lds(
      (const __attribute__((address_space(1))) unsigned int*)g,
      (__attribute__((address_space(3))) unsigned int*)l, 16, 0, 0);
}

// ---------- x: [B][C][N] f32  ->  xt: [B][N][C] bf16 (transpose + convert) ----------
__global__ void k_prep_x(const float* __restrict__ x, unsigned short* __restrict__ xt) {
  __shared__ float tile[32][33];
  int bid = blockIdx.x;
  int nt = bid & 31, ct = (bid >> 5) & 15, b = bid >> 9;
  int n0 = nt * 32, c0 = ct * 32;
  int t = threadIdx.x;
  int r = t >> 3, q = t & 7;
  float4 v = *(const float4*)(x + ((size_t)(b * NC + c0 + r)) * NPIX + n0 + q * 4);
  tile[r][q * 4 + 0] = v.x; tile[r][q * 4 + 1] = v.y;
  tile[r][q * 4 + 2] = v.z; tile[r][q * 4 + 3] = v.w;
  __syncthreads();
  int cl = q * 4;
  u16x4 o;
  o[0] = f2bf(tile[cl + 0][r]); o[1] = f2bf(tile[cl + 1][r]);
  o[2] = f2bf(tile[cl + 2][r]); o[3] = f2bf(tile[cl + 3][r]);
  *(u16x4*)(xt + ((size_t)(b * NPIX + n0 + r)) * NC + c0 + cl) = o;
}

// ---------- weights f32 -> bf16, wb[3][512][512] ----------
__global__ void k_prep_w(const float* __restrict__ wq, const float* __restrict__ wk,
                         const float* __restrict__ wv, unsigned short* __restrict__ wb) {
  const float* src = blockIdx.y == 0 ? wq : (blockIdx.y == 1 ? wk : wv);
  unsigned short* dst = wb + (size_t)blockIdx.y * NC * NC;
  for (int i = blockIdx.x * 256 + threadIdx.x; i < NC * NC / 4; i += gridDim.x * 256) {
    float4 v = ((const float4*)src)[i];
    u16x4 o = { f2bf(v.x), f2bf(v.y), f2bf(v.z), f2bf(v.w) };
    ((u16x4*)dst)[i] = o;
  }
}

// ---------- QKV projection GEMM ----------
// C[m][n] = sum_c w[m][c] * xt[n][c];   128x128 tile, BK=64, 4 waves, 16x16x32 MFMA.
// p==0: Q -> (acc+bias)*scale stored transposed [b][hd][n][e]
// p==1: K -> acc+bias+rh+rw  stored transposed [b][hd][n][e]
// p==2: V -> acc+bias        stored natural    [b][hd][e][n]
__global__ __launch_bounds__(256, 2) void k_qkv(
    const unsigned short* __restrict__ wb, const unsigned short* __restrict__ xt,
    const float* __restrict__ qb, const float* __restrict__ kb, const float* __restrict__ vb,
    const float* __restrict__ rh, const float* __restrict__ rw,
    unsigned short* __restrict__ Qs, unsigned short* __restrict__ Kn,
    unsigned short* __restrict__ Vm) {
  __shared__ unsigned short Alds[128 * 64];
  __shared__ unsigned short Blds[128 * 64];
  int bid = blockIdx.x;
  int nt = bid & 7, mt = (bid >> 3) & 3;
  int rest = bid >> 5;
  int p = rest % 3, b = rest / 3;
  int m0 = mt * 128, n0 = nt * 128;
  const unsigned short* A = wb + (size_t)p * NC * NC + (size_t)m0 * NC;
  const unsigned short* Bx = xt + (size_t)b * NPIX * NC + (size_t)n0 * NC;
  int t = threadIdx.x;
  int lane = t & 63, wid = t >> 6;
  int wm = (wid >> 1) * 64, wn = (wid & 1) * 64;
  f32x4 acc[4][4] = {};
  for (int k0 = 0; k0 < NC; k0 += 64) {
#pragma unroll
    for (int i = 0; i < 4; i++) {
      int idx = i * 256 + t;
      int row = idx >> 3, col = (idx & 7) * 8;
      gload_lds16(A + (size_t)row * NC + k0 + col, &Alds[idx * 8]);
    }
#pragma unroll
    for (int i = 0; i < 4; i++) {
      int idx = i * 256 + t;
      int row = idx >> 3, col = (idx & 7) * 8;
      gload_lds16(Bx + (size_t)row * NC + k0 + col, &Blds[idx * 8]);
    }
    __syncthreads();
#pragma unroll
    for (int ks = 0; ks < 2; ks++) {
      int kk = ks * 32 + ((lane >> 4) << 3);
      bf16x8 af[4], bfr[4];
#pragma unroll
      for (int f = 0; f < 4; f++)
        af[f] = *(const bf16x8*)&Alds[(wm + f * 16 + (lane & 15)) * 64 + kk];
#pragma unroll
      for (int f = 0; f < 4; f++)
        bfr[f] = *(const bf16x8*)&Blds[(wn + f * 16 + (lane & 15)) * 64 + kk];
#pragma unroll
      for (int fm = 0; fm < 4; fm++)
#pragma unroll
        for (int fn = 0; fn < 4; fn++)
          acc[fm][fn] = __builtin_amdgcn_mfma_f32_16x16x32_bf16(af[fm], bfr[fn], acc[fm][fn], 0, 0, 0);
    }
    __syncthreads();
  }
  const float scale = 0.044194173824159216f;  // 512^-0.5
  if (p == 2) {
    unsigned short* dst = Vm + ((size_t)(b * NC + m0)) * NPIX + n0;
#pragma unroll
    for (int fm = 0; fm < 4; fm++) {
#pragma unroll
      for (int r = 0; r < 4; r++) {
        int mrow = wm + fm * 16 + ((lane >> 4) << 2) + r;
        float bv = vb[m0 + mrow];
#pragma unroll
        for (int fn = 0; fn < 4; fn++) {
          int ncol = wn + fn * 16 + (lane & 15);
          dst[(size_t)mrow * NPIX + ncol] = f2bf(acc[fm][fn][r] + bv);
        }
      }
    }
  } else {
    const float* bias = (p == 0) ? qb : kb;
    unsigned short* dst = ((p == 0) ? Qs : Kn) + ((size_t)((b * NHEADS + mt) * NPIX + n0)) * NEMB;
#pragma unroll
    for (int fm = 0; fm < 4; fm++) {
      int e0 = wm + fm * 16 + ((lane >> 4) << 2);
      int mg = m0 + e0;
#pragma unroll
      for (int fn = 0; fn < 4; fn++) {
        int ncol = wn + fn * 16 + (lane & 15);
        int j = n0 + ncol;
        u16x4 o;
#pragma unroll
        for (int r = 0; r < 4; r++) {
          float v = acc[fm][fn][r] + bias[mg + r];
          if (p == 0) v *= scale;
          else v += rh[(mg + r) * 32 + (j & 31)] + rw[(mg + r) * 32 + (j >> 5)];
          o[r] = f2bf(v);
        }
        *(u16x4*)&dst[(size_t)ncol * NEMB + e0] = o;
      }
    }
  }
}

// ---------- flash attention v2: wave-independent, no K/V staging, no barriers ----------
// grid = 1024: (b, hd, 64-row i-tile); 4 waves x 16 q-rows each, fully independent.
// K/V fragments read directly from global (L2-resident: 512KB per (b,hd)).
// Only LDS use: per-wave-private P transpose buffer (no __syncthreads anywhere).
__global__ __launch_bounds__(256, 4) void k_attn(
    const unsigned short* __restrict__ Qs, const unsigned short* __restrict__ Kn,
    const unsigned short* __restrict__ Vm, float* __restrict__ out) {
  __shared__ unsigned short Plds[4 * 16 * 72];  // 9216 B; [wave][16 rows][64+8 pad]
  int bid = blockIdx.x;
  int pair = bid & 63, it16 = bid >> 6;  // bid&7 == pair&7 -> all i-tiles of a pair on one XCD
  int b = pair >> 2, hd = pair & 3;
  int t = threadIdx.x, w = t >> 6, lane = t & 63;
  int l15 = lane & 15, hi = lane >> 4;
  int i0 = it16 * 64 + w * 16;
  const unsigned short* Qb = Qs + ((size_t)(b * NHEADS + hd)) * NPIX * NEMB;
  const unsigned short* Kb = Kn + ((size_t)(b * NHEADS + hd)) * NPIX * NEMB;
  const unsigned short* Vb = Vm + ((size_t)(b * NHEADS + hd)) * NEMB * NPIX;
  unsigned short* Pw = Plds + w * (16 * 72);

  // Q fragments: 16 rows x 128 e, register-resident (16 VGPR)
  bf16x8 qf[4];
#pragma unroll
  for (int ks = 0; ks < 4; ks++)
    qf[ks] = *(const bf16x8*)&Qb[(size_t)(i0 + l15) * NEMB + ks * 32 + hi * 8];

  f32x4 yacc[8] = {};
  float mrow[4], lrow[4];
#pragma unroll
  for (int r = 0; r < 4; r++) { mrow[r] = -3.0e38f; lrow[r] = 0.f; }

  for (int j0 = 0; j0 < NPIX; j0 += 64) {
    // S = Q K'^T : 16x64 per wave, K frags direct from global ([n][e], 16B contig)
    f32x4 sacc[4] = {};
#pragma unroll
    for (int ks = 0; ks < 4; ks++) {
      bf16x8 kf[4];
#pragma unroll
      for (int jt = 0; jt < 4; jt++)
        kf[jt] = *(const bf16x8*)&Kb[(size_t)(j0 + jt * 16 + l15) * NEMB + ks * 32 + hi * 8];
      __builtin_amdgcn_s_setprio(1);
#pragma unroll
      for (int jt = 0; jt < 4; jt++)
        sacc[jt] = __builtin_amdgcn_mfma_f32_16x16x32_bf16(qf[ks], kf[jt], sacc[jt], 0, 0, 0);
      __builtin_amdgcn_s_setprio(0);
    }
    // online softmax; lane's rows are i_local = 4*hi + r, cols spread over 16 l15 lanes
    float corr[4];
#pragma unroll
    for (int r = 0; r < 4; r++) {
      float cm = fmaxf(fmaxf(sacc[0][r], sacc[1][r]), fmaxf(sacc[2][r], sacc[3][r]));
      cm = fmaxf(cm, __shfl_xor(cm, 1));
      cm = fmaxf(cm, __shfl_xor(cm, 2));
      cm = fmaxf(cm, __shfl_xor(cm, 4));
      cm = fmaxf(cm, __shfl_xor(cm, 8));
      float mo = mrow[r];
      float mn = fmaxf(mo, cm);
      corr[r] = __expf(mo - mn);
      mrow[r] = mn;
      float rs = 0.f;
#pragma unroll
      for (int jt = 0; jt < 4; jt++) {
        float pv = __expf(sacc[jt][r] - mn);
        sacc[jt][r] = pv;
        rs += pv;
      }
      rs += __shfl_xor(rs, 1);
      rs += __shfl_xor(rs, 2);
      rs += __shfl_xor(rs, 4);
      rs += __shfl_xor(rs, 8);
      lrow[r] = lrow[r] * corr[r] + rs;
    }
#pragma unroll
    for (int et = 0; et < 8; et++)
#pragma unroll
      for (int r = 0; r < 4; r++) yacc[et][r] *= corr[r];
    // P -> bf16 -> per-wave-private LDS (transpose to A-frag layout); same-wave RAW,
    // compiler inserts lgkmcnt — no barrier needed.
#pragma unroll
    for (int jt = 0; jt < 4; jt++)
#pragma unroll
      for (int r = 0; r < 4; r++)
        Pw[(hi * 4 + r) * 72 + jt * 16 + l15] = f2bf(sacc[jt][r]);
    // y += P V : V frags direct from global ([e][n], 16B contig)
#pragma unroll
    for (int ks = 0; ks < 2; ks++) {
      bf16x8 pf = *(const bf16x8*)&Pw[l15 * 72 + ks * 32 + hi * 8];
      __builtin_amdgcn_s_setprio(1);
#pragma unroll
      for (int et = 0; et < 8; et++) {
        bf16x8 vf = *(const bf16x8*)&Vb[(size_t)(et * 16 + l15) * NPIX + j0 + ks * 32 + hi * 8];
        yacc[et] = __builtin_amdgcn_mfma_f32_16x16x32_bf16(pf, vf, yacc[et], 0, 0, 0);
      }
      __builtin_amdgcn_s_setprio(0);
    }
  }
  // epilogue: out[b][hd*128 + (i>>3)][(i&7)*128 + e] = y[i][e]/l
#pragma unroll
  for (int r = 0; r < 4; r++) {
    int i = i0 + hi * 4 + r;
    float sc = 1.0f / lrow[r];
    float* orow = out + ((size_t)(b * NC + hd * NEMB + (i >> 3))) * NPIX + (i & 7) * NEMB;
#pragma unroll
    for (int et = 0; et < 8; et++)
      orow[et * 16 + l15] = yacc[et][r] * sc;
  }
}

extern "C" void kernel_launch(void* const* d_in, const int* in_sizes, int n_in,
                              void* d_out, int out_size, void* d_ws, size_t ws_size,
                              hipStream_t stream) {
  const float* x  = (const float*)d_in[0];
  const float* wq = (const float*)d_in[1];
  const float* qb = (const float*)d_in[2];
  const float* wk = (const float*)d_in[3];
  const float* kb = (const float*)d_in[4];
  const float* wv = (const float*)d_in[5];
  const float* vb = (const float*)d_in[6];
  const float* rh = (const float*)d_in[7];
  const float* rw = (const float*)d_in[8];
  float* out = (float*)d_out;
  char* ws = (char*)d_ws;
  // ws layout (bytes): xt 16,777,216 | wb 1,572,864 | Q 16,777,216 | K 16,777,216 | V 16,777,216
  unsigned short* xt = (unsigned short*)(ws);
  unsigned short* wb = (unsigned short*)(ws + 16777216);
  unsigned short* Q  = (unsigned short*)(ws + 18350080);
  unsigned short* K  = (unsigned short*)(ws + 35127296);
  unsigned short* V  = (unsigned short*)(ws + 51904512);
  k_prep_x<<<8192, 256, 0, stream>>>(x, xt);
  k_prep_w<<<dim3(64, 3), 256, 0, stream>>>(wq, wk, wv, wb);
  k_qkv<<<1536, 256, 0, stream>>>(wb, xt, qb, kb, vb, rh, rw, Q, K, V);
  k_attn<<<1024, 256, 0, stream>>>(Q, K, V, out);
}

// Round 3
// 143.735 us; speedup vs baseline: 2.1327x; 2.1327x over previous
//
#include <hip/hip_runtime.h>
#include <hip/hip_bf16.h>
#include <cstdint>

#define NB 16
#define NC 512
#define NPIX 1024
#define NHEADS 4
#define NEMB 128

typedef short bf16x8 __attribute__((ext_vector_type(8)));
typedef float f32x4 __attribute__((ext_vector_type(4)));
typedef unsigned short u16x4 __attribute__((ext_vector_type(4)));
typedef unsigned short u16x8 __attribute__((ext_vector_type(8)));

__device__ __forceinline__ unsigned short f2bf(float f) {
  union { float f; unsigned u; } c; c.f = f;
  return (unsigned short)((c.u + 0x7FFFu + ((c.u >> 16) & 1u)) >> 16);
}

__device__ __forceinline__ void gload_lds16(const void* g, void* l) {
  __builtin_amdgcn_global_load_lds(
      (const __attribute__((address_space(1))) unsigned int*)g,
      (__attribute__((address_space(3))) unsigned int*)l, 16, 0, 0);
}

// ---------- x: [B][C][N] f32  ->  xt: [B][N][C] bf16 (transpose + convert) ----------
__global__ void k_prep_x(const float* __restrict__ x, unsigned short* __restrict__ xt) {
  __shared__ float tile[32][33];
  int bid = blockIdx.x;
  int nt = bid & 31, ct = (bid >> 5) & 15, b = bid >> 9;
  int n0 = nt * 32, c0 = ct * 32;
  int t = threadIdx.x;
  int r = t >> 3, q = t & 7;
  float4 v = *(const float4*)(x + ((size_t)(b * NC + c0 + r)) * NPIX + n0 + q * 4);
  tile[r][q * 4 + 0] = v.x; tile[r][q * 4 + 1] = v.y;
  tile[r][q * 4 + 2] = v.z; tile[r][q * 4 + 3] = v.w;
  __syncthreads();
  int cl = q * 4;
  u16x4 o;
  o[0] = f2bf(tile[cl + 0][r]); o[1] = f2bf(tile[cl + 1][r]);
  o[2] = f2bf(tile[cl + 2][r]); o[3] = f2bf(tile[cl + 3][r]);
  *(u16x4*)(xt + ((size_t)(b * NPIX + n0 + r)) * NC + c0 + cl) = o;
}

// ---------- weights f32 -> bf16, wb[3][512][512] ----------
__global__ void k_prep_w(const float* __restrict__ wq, const float* __restrict__ wk,
                         const float* __restrict__ wv, unsigned short* __restrict__ wb) {
  const float* src = blockIdx.y == 0 ? wq : (blockIdx.y == 1 ? wk : wv);
  unsigned short* dst = wb + (size_t)blockIdx.y * NC * NC;
  for (int i = blockIdx.x * 256 + threadIdx.x; i < NC * NC / 4; i += gridDim.x * 256) {
    float4 v = ((const float4*)src)[i];
    u16x4 o = { f2bf(v.x), f2bf(v.y), f2bf(v.z), f2bf(v.w) };
    ((u16x4*)dst)[i] = o;
  }
}

// ---------- QKV projection GEMM ----------
// p==0: Q -> (acc+bias)*scale*log2e stored transposed [b][hd][n][e]   (exp2-domain)
// p==1: K -> acc+bias+rh+rw  stored transposed [b][hd][n][e]
// p==2: V -> acc+bias        stored natural    [b][hd][e][n]
__global__ __launch_bounds__(256, 2) void k_qkv(
    const unsigned short* __restrict__ wb, const unsigned short* __restrict__ xt,
    const float* __restrict__ qb, const float* __restrict__ kb, const float* __restrict__ vb,
    const float* __restrict__ rh, const float* __restrict__ rw,
    unsigned short* __restrict__ Qs, unsigned short* __restrict__ Kn,
    unsigned short* __restrict__ Vm) {
  __shared__ unsigned short Alds[128 * 64];
  __shared__ unsigned short Blds[128 * 64];
  int bid = blockIdx.x;
  int nt = bid & 7, mt = (bid >> 3) & 3;
  int rest = bid >> 5;
  int p = rest % 3, b = rest / 3;
  int m0 = mt * 128, n0 = nt * 128;
  const unsigned short* A = wb + (size_t)p * NC * NC + (size_t)m0 * NC;
  const unsigned short* Bx = xt + (size_t)b * NPIX * NC + (size_t)n0 * NC;
  int t = threadIdx.x;
  int lane = t & 63, wid = t >> 6;
  int wm = (wid >> 1) * 64, wn = (wid & 1) * 64;
  f32x4 acc[4][4] = {};
  for (int k0 = 0; k0 < NC; k0 += 64) {
#pragma unroll
    for (int i = 0; i < 4; i++) {
      int idx = i * 256 + t;
      int row = idx >> 3, col = (idx & 7) * 8;
      gload_lds16(A + (size_t)row * NC + k0 + col, &Alds[idx * 8]);
    }
#pragma unroll
    for (int i = 0; i < 4; i++) {
      int idx = i * 256 + t;
      int row = idx >> 3, col = (idx & 7) * 8;
      gload_lds16(Bx + (size_t)row * NC + k0 + col, &Blds[idx * 8]);
    }
    __syncthreads();
#pragma unroll
    for (int ks = 0; ks < 2; ks++) {
      int kk = ks * 32 + ((lane >> 4) << 3);
      bf16x8 af[4], bfr[4];
#pragma unroll
      for (int f = 0; f < 4; f++)
        af[f] = *(const bf16x8*)&Alds[(wm + f * 16 + (lane & 15)) * 64 + kk];
#pragma unroll
      for (int f = 0; f < 4; f++)
        bfr[f] = *(const bf16x8*)&Blds[(wn + f * 16 + (lane & 15)) * 64 + kk];
#pragma unroll
      for (int fm = 0; fm < 4; fm++)
#pragma unroll
        for (int fn = 0; fn < 4; fn++)
          acc[fm][fn] = __builtin_amdgcn_mfma_f32_16x16x32_bf16(af[fm], bfr[fn], acc[fm][fn], 0, 0, 0);
    }
    __syncthreads();
  }
  // 512^-0.5 * log2(e): softmax runs in exp2 domain
  const float scale = 0.044194173824159216f * 1.4426950408889634f;
  if (p == 2) {
    unsigned short* dst = Vm + ((size_t)(b * NC + m0)) * NPIX + n0;
#pragma unroll
    for (int fm = 0; fm < 4; fm++) {
#pragma unroll
      for (int r = 0; r < 4; r++) {
        int mrow = wm + fm * 16 + ((lane >> 4) << 2) + r;
        float bv = vb[m0 + mrow];
#pragma unroll
        for (int fn = 0; fn < 4; fn++) {
          int ncol = wn + fn * 16 + (lane & 15);
          dst[(size_t)mrow * NPIX + ncol] = f2bf(acc[fm][fn][r] + bv);
        }
      }
    }
  } else {
    const float* bias = (p == 0) ? qb : kb;
    unsigned short* dst = ((p == 0) ? Qs : Kn) + ((size_t)((b * NHEADS + mt) * NPIX + n0)) * NEMB;
#pragma unroll
    for (int fm = 0; fm < 4; fm++) {
      int e0 = wm + fm * 16 + ((lane >> 4) << 2);
      int mg = m0 + e0;
#pragma unroll
      for (int fn = 0; fn < 4; fn++) {
        int ncol = wn + fn * 16 + (lane & 15);
        int j = n0 + ncol;
        u16x4 o;
#pragma unroll
        for (int r = 0; r < 4; r++) {
          float v = acc[fm][fn][r] + bias[mg + r];
          if (p == 0) v *= scale;
          else v += rh[(mg + r) * 32 + (j & 31)] + rw[(mg + r) * 32 + (j >> 5)];
          o[r] = f2bf(v);
        }
        *(u16x4*)&dst[(size_t)ncol * NEMB + e0] = o;
      }
    }
  }
}

// ---------- flash attention v3: staged LDS (r1 layout) + T14 async-STAGE + ----------
// ---------- T13 defer-max + exp2 softmax + T5 setprio                      ----------
// grid = 512: (b, hd, 128-row i-tile); 4 waves x 32 q-rows; KV tiles of 64.
__global__ __launch_bounds__(256, 2) void k_attn(
    const unsigned short* __restrict__ Qs, const unsigned short* __restrict__ Kn,
    const unsigned short* __restrict__ Vm, float* __restrict__ out) {
  __shared__ __align__(16) char smem[54272];
  unsigned short* Klds = (unsigned short*)smem;            // [64][136]  (pad 8)
  unsigned short* Vlds = (unsigned short*)(smem + 17408);  // [128][72]  (pad 8)
  unsigned short* Plds = (unsigned short*)(smem + 35840);  // [4][32][72]
  int bid = blockIdx.x;
  int pair = bid & 63, it8 = bid >> 6;  // all i-tiles of a (b,hd) share bid%8 -> same XCD L2
  int b = pair >> 2, hd = pair & 3;
  int i0 = it8 * 128;
  int t = threadIdx.x, w = t >> 6, lane = t & 63;
  int l15 = lane & 15, hi = lane >> 4;
  const unsigned short* Qb = Qs + ((size_t)(b * NHEADS + hd)) * NPIX * NEMB;
  const unsigned short* Kb = Kn + ((size_t)(b * NHEADS + hd)) * NPIX * NEMB;
  const unsigned short* Vb = Vm + ((size_t)(b * NHEADS + hd)) * NEMB * NPIX;
  unsigned short* Pw = Plds + w * (32 * 72);

  // per-thread staging coordinates (K: [64 j][128 e], V: [128 e][64 j])
  int kj = t >> 4, keo = (t & 15) * 8;   // K row base (i*16 + kj), col
  int ve = t >> 3, vjo = (t & 7) * 8;    // V row base (i*32 + ve), col

  // Q fragments: 32 rows/wave x 128 e, register-resident
  bf16x8 qf[2][4];
#pragma unroll
  for (int it = 0; it < 2; it++) {
    int row = i0 + w * 32 + it * 16 + l15;
#pragma unroll
    for (int ks = 0; ks < 4; ks++)
      qf[it][ks] = *(const bf16x8*)&Qb[(size_t)row * NEMB + ks * 32 + hi * 8];
  }
  f32x4 yacc[2][8] = {};
  float mrow[2][4], lrow[2][4];
#pragma unroll
  for (int it = 0; it < 2; it++)
#pragma unroll
    for (int r = 0; r < 4; r++) { mrow[it][r] = -3.0e38f; lrow[it][r] = 0.f; }

  u16x8 kr[4], vr[4];
  // prologue: stage tile 0
#pragma unroll
  for (int i = 0; i < 4; i++) {
    kr[i] = *(const u16x8*)&Kb[(size_t)(i * 16 + kj) * NEMB + keo];
    vr[i] = *(const u16x8*)&Vb[(size_t)(i * 32 + ve) * NPIX + vjo];
  }
#pragma unroll
  for (int i = 0; i < 4; i++) {
    *(u16x8*)&Klds[(i * 16 + kj) * 136 + keo] = kr[i];
    *(u16x8*)&Vlds[(i * 32 + ve) * 72 + vjo] = vr[i];
  }
  __syncthreads();

  const float THR = 11.5415603f;  // 8 nats in log2 domain

  for (int tt = 0; tt < 16; tt++) {
    // T14: issue next tile's global loads BEFORE compute — latency hides under MFMA+VALU
    if (tt < 15) {
      int j0n = (tt + 1) * 64;
#pragma unroll
      for (int i = 0; i < 4; i++) {
        kr[i] = *(const u16x8*)&Kb[(size_t)(j0n + i * 16 + kj) * NEMB + keo];
        vr[i] = *(const u16x8*)&Vb[(size_t)(i * 32 + ve) * NPIX + j0n + vjo];
      }
    }
    // S = Q K'^T  (32x64 per wave)
    f32x4 sacc[2][4] = {};
#pragma unroll
    for (int ks = 0; ks < 4; ks++) {
      int kk = ks * 32 + hi * 8;
      bf16x8 kf[4];
#pragma unroll
      for (int jt = 0; jt < 4; jt++)
        kf[jt] = *(const bf16x8*)&Klds[(jt * 16 + l15) * 136 + kk];
      __builtin_amdgcn_s_setprio(1);
#pragma unroll
      for (int it = 0; it < 2; it++)
#pragma unroll
        for (int jt = 0; jt < 4; jt++)
          sacc[it][jt] = __builtin_amdgcn_mfma_f32_16x16x32_bf16(qf[it][ks], kf[jt], sacc[it][jt], 0, 0, 0);
      __builtin_amdgcn_s_setprio(0);
    }
    // online softmax (exp2 domain), T13 defer-max
    float cm[2][4];
    bool need = false;
#pragma unroll
    for (int it = 0; it < 2; it++) {
#pragma unroll
      for (int r = 0; r < 4; r++) {
        float c = fmaxf(fmaxf(sacc[it][0][r], sacc[it][1][r]),
                        fmaxf(sacc[it][2][r], sacc[it][3][r]));
        c = fmaxf(c, __shfl_xor(c, 1));
        c = fmaxf(c, __shfl_xor(c, 2));
        c = fmaxf(c, __shfl_xor(c, 4));
        c = fmaxf(c, __shfl_xor(c, 8));
        cm[it][r] = c;
        need |= (c - mrow[it][r] > THR);
      }
    }
    if (__any(need)) {
#pragma unroll
      for (int it = 0; it < 2; it++) {
#pragma unroll
        for (int r = 0; r < 4; r++) {
          float mo = mrow[it][r];
          float mn = fmaxf(mo, cm[it][r]);
          float corr = exp2f(mo - mn);
          mrow[it][r] = mn;
          lrow[it][r] *= corr;
#pragma unroll
          for (int et = 0; et < 8; et++) yacc[it][et][r] *= corr;
        }
      }
    }
#pragma unroll
    for (int it = 0; it < 2; it++) {
#pragma unroll
      for (int r = 0; r < 4; r++) {
        float m = mrow[it][r];
        float rs = 0.f;
#pragma unroll
        for (int jt = 0; jt < 4; jt++) {
          float pv = exp2f(sacc[it][jt][r] - m);
          sacc[it][jt][r] = pv;
          rs += pv;
        }
        rs += __shfl_xor(rs, 1);
        rs += __shfl_xor(rs, 2);
        rs += __shfl_xor(rs, 4);
        rs += __shfl_xor(rs, 8);
        lrow[it][r] += rs;
      }
    }
    // P -> bf16 -> per-wave-private LDS (A-frag layout; same-wave RAW, no barrier)
#pragma unroll
    for (int it = 0; it < 2; it++)
#pragma unroll
      for (int jt = 0; jt < 4; jt++)
#pragma unroll
        for (int r = 0; r < 4; r++)
          Pw[(it * 16 + hi * 4 + r) * 72 + jt * 16 + l15] = f2bf(sacc[it][jt][r]);
    // y += P V
#pragma unroll
    for (int ks = 0; ks < 2; ks++) {
      int kk = ks * 32 + hi * 8;
      bf16x8 pf[2];
#pragma unroll
      for (int it = 0; it < 2; it++)
        pf[it] = *(const bf16x8*)&Pw[(it * 16 + l15) * 72 + kk];
      __builtin_amdgcn_s_setprio(1);
#pragma unroll
      for (int et = 0; et < 8; et++) {
        bf16x8 vf = *(const bf16x8*)&Vlds[(et * 16 + l15) * 72 + kk];
#pragma unroll
        for (int it = 0; it < 2; it++)
          yacc[it][et] = __builtin_amdgcn_mfma_f32_16x16x32_bf16(pf[it], vf, yacc[it][et], 0, 0, 0);
      }
      __builtin_amdgcn_s_setprio(0);
    }
    // swap in the prefetched tile
    if (tt < 15) {
      __syncthreads();  // all waves done reading current tile
#pragma unroll
      for (int i = 0; i < 4; i++) {
        *(u16x8*)&Klds[(i * 16 + kj) * 136 + keo] = kr[i];
        *(u16x8*)&Vlds[(i * 32 + ve) * 72 + vjo] = vr[i];
      }
      __syncthreads();  // writes visible before next compute
    }
  }
  // epilogue: out[b][hd*128 + (i>>3)][(i&7)*128 + e] = y[i][e]/l
#pragma unroll
  for (int it = 0; it < 2; it++) {
#pragma unroll
    for (int r = 0; r < 4; r++) {
      int i = i0 + w * 32 + it * 16 + hi * 4 + r;
      float sc = 1.0f / lrow[it][r];
      float* orow = out + ((size_t)(b * NC + hd * NEMB + (i >> 3))) * NPIX + (i & 7) * NEMB;
#pragma unroll
      for (int et = 0; et < 8; et++)
        orow[et * 16 + l15] = yacc[it][et][r] * sc;
    }
  }
}

extern "C" void kernel_launch(void* const* d_in, const int* in_sizes, int n_in,
                              void* d_out, int out_size, void* d_ws, size_t ws_size,
                              hipStream_t stream) {
  const float* x  = (const float*)d_in[0];
  const float* wq = (const float*)d_in[1];
  const float* qb = (const float*)d_in[2];
  const float* wk = (const float*)d_in[3];
  const float* kb = (const float*)d_in[4];
  const float* wv = (const float*)d_in[5];
  const float* vb = (const float*)d_in[6];
  const float* rh = (const float*)d_in[7];
  const float* rw = (const float*)d_in[8];
  float* out = (float*)d_out;
  char* ws = (char*)d_ws;
  // ws layout (bytes): xt 16,777,216 | wb 1,572,864 | Q 16,777,216 | K 16,777,216 | V 16,777,216
  unsigned short* xt = (unsigned short*)(ws);
  unsigned short* wb = (unsigned short*)(ws + 16777216);
  unsigned short* Q  = (unsigned short*)(ws + 18350080);
  unsigned short* K  = (unsigned short*)(ws + 35127296);
  unsigned short* V  = (unsigned short*)(ws + 51904512);
  k_prep_x<<<8192, 256, 0, stream>>>(x, xt);
  k_prep_w<<<dim3(64, 3), 256, 0, stream>>>(wq, wk, wv, wb);
  k_qkv<<<1536, 256, 0, stream>>>(wb, xt, qb, kb, vb, rh, rw, Q, K, V);
  k_attn<<<512, 256, 0, stream>>>(Q, K, V, out);
}